// Round 1
// baseline (876.609 us; speedup 1.0000x reference)
//
#include <hip/hip_runtime.h>

// DiffMoE fused step, MI355X gfx950.
// D=1024, DD=4096, N_EXP=8, BS=8192, k=1024 (TRAIN_CAP=1.0).
// Pipeline: gating -> exact top-k per expert (rank count) -> cp GEMM+gelu ->
// logits+softplus loss -> LN gather -> per-expert FC1(gelu) -> FC2 -> combine.
// All GEMMs: bf16 MFMA 16x16x32, 128x128 tiles, fp32 weights converted during
// LDS staging. Workspace ~135 MB.

#define BS_   8192
#define D_    1024
#define DD_   4096
#define NEXP  8
#define KCAP  1024

typedef unsigned int   uint32;
typedef unsigned short u16;
typedef __bf16 bf16x8  __attribute__((ext_vector_type(8)));
typedef float  f32x4   __attribute__((ext_vector_type(4)));
typedef u16    u16x8   __attribute__((ext_vector_type(8)));
typedef u16    u16x4   __attribute__((ext_vector_type(4)));

__device__ __forceinline__ u16 f2bf(float f){
  uint32 u = __float_as_uint(f);
  u = (u + 0x7fffu + ((u >> 16) & 1u)) >> 16;   // RNE
  return (u16)u;
}
__device__ __forceinline__ float bf_lo(uint32 u){ return __uint_as_float(u << 16); }
__device__ __forceinline__ float bf_hi(uint32 u){ return __uint_as_float(u & 0xffff0000u); }
__device__ __forceinline__ float gelu_tanh(float v){
  return 0.5f * v * (1.0f + tanhf(0.7978845608028654f * (v + 0.044715f * v * v * v)));
}

// ---------------------------------------------------------------- gating ----
// scores[i][e] = (tanh(x[i].Wg[e]) + 1) * 0.5 ; also zero keep_bits[i].
__global__ __launch_bounds__(64)
void gating_kernel(const float* __restrict__ x, const float* __restrict__ Wg,
                   float* __restrict__ scores, uint32* __restrict__ keep_bits)
{
  const int i    = blockIdx.x;
  const int lane = threadIdx.x;
  const float* xr = x + (size_t)i * D_ + lane * 16;
  const float4 x0 = *(const float4*)(xr +  0);
  const float4 x1 = *(const float4*)(xr +  4);
  const float4 x2 = *(const float4*)(xr +  8);
  const float4 x3 = *(const float4*)(xr + 12);
  float acc[NEXP];
  #pragma unroll
  for (int e = 0; e < NEXP; e++){
    const float* wr = Wg + e * D_ + lane * 16;
    const float4 w0 = *(const float4*)(wr +  0);
    const float4 w1 = *(const float4*)(wr +  4);
    const float4 w2 = *(const float4*)(wr +  8);
    const float4 w3 = *(const float4*)(wr + 12);
    float s = x0.x*w0.x + x0.y*w0.y + x0.z*w0.z + x0.w*w0.w;
    s += x1.x*w1.x + x1.y*w1.y + x1.z*w1.z + x1.w*w1.w;
    s += x2.x*w2.x + x2.y*w2.y + x2.z*w2.z + x2.w*w2.w;
    s += x3.x*w3.x + x3.y*w3.y + x3.z*w3.z + x3.w*w3.w;
    acc[e] = s;
  }
  #pragma unroll
  for (int e = 0; e < NEXP; e++){
    #pragma unroll
    for (int off = 32; off >= 1; off >>= 1) acc[e] += __shfl_xor(acc[e], off);
  }
  if (lane == 0){
    #pragma unroll
    for (int e = 0; e < NEXP; e++) scores[i * NEXP + e] = (tanhf(acc[e]) + 1.0f) * 0.5f;
    keep_bits[i] = 0u;
  }
}

// ------------------------------------------------------------- selection ----
// Exact top-k via rank count; key = (score_bits<<32)|(8191-i) so higher score
// wins, ties -> lower index (matches stable argsort of -scores). Keys are
// distinct by construction -> exactly KCAP selected per expert.
__global__ __launch_bounds__(256)
void select_kernel(const float* __restrict__ scores, uint32* __restrict__ keep_bits,
                   int* __restrict__ counts, int* __restrict__ rowlist,
                   float* __restrict__ wlist, int* __restrict__ inv)
{
  __shared__ unsigned long long sk[2048];
  const int e = blockIdx.y;
  const int i = blockIdx.x * 256 + threadIdx.x;
  const float ms = scores[i * NEXP + e];
  const unsigned long long mk =
      ((unsigned long long)__float_as_uint(ms) << 32) | (uint32)(BS_ - 1 - i);
  int cnt = 0;
  for (int base = 0; base < BS_; base += 2048){
    #pragma unroll
    for (int u = 0; u < 8; u++){
      const int j = base + (int)threadIdx.x * 8 + u;
      const float sj = scores[j * NEXP + e];
      sk[threadIdx.x * 8 + u] =
          ((unsigned long long)__float_as_uint(sj) << 32) | (uint32)(BS_ - 1 - j);
    }
    __syncthreads();
    #pragma unroll 8
    for (int jj = 0; jj < 2048; jj++) cnt += (sk[jj] > mk) ? 1 : 0;
    __syncthreads();
  }
  if (cnt < KCAP){
    const int slot = atomicAdd(&counts[e], 1);
    rowlist[e * KCAP + slot] = i;
    wlist[e * KCAP + slot]   = ms;
    inv[i * NEXP + e]        = slot;
    atomicOr(&keep_bits[i], 1u << e);
  }
}

// ------------------------------------------------------------------ GEMM ----
// C[m][n] = sum_k A[m][k] * B[n][k]  (+bias[n], opt gelu). A: fp32 or bf16,
// B: fp32 (converted to bf16 in staging). 128x128 tile, BK=32, 4 waves each
// computing 64x64 via 4x4 MFMA 16x16x32. LDS rows padded to 40 bf16.
template<bool A_BF16, bool GELU_EP, bool OUT_BF16>
__global__ __launch_bounds__(256)
void gemm_bt(const void* __restrict__ Av, const float* __restrict__ B,
             const float* __restrict__ bias, void* __restrict__ Cv,
             int M, int N, int K,
             long long sA, long long sB, long long sBias, long long sC)
{
  __shared__ u16 smA[128 * 40];
  __shared__ u16 smB[128 * 40];
  const int z    = blockIdx.z;
  const int m0   = blockIdx.y * 128;
  const int n0   = blockIdx.x * 128;
  const int tid  = threadIdx.x;
  const int srow = tid >> 1;
  const int scol = (tid & 1) * 16;
  const int lane = tid & 63, wv = tid >> 6;
  const int l15  = lane & 15, quad = lane >> 4;
  const int moff = (wv >> 1) * 64, noff = (wv & 1) * 64;

  const float* Bp  = B + (long long)z * sB + (long long)(n0 + srow) * K + scol;
  const float* Apf = nullptr; const u16* Aph = nullptr;
  if constexpr (A_BF16) Aph = (const u16*)Av  + (long long)z * sA + (long long)(m0 + srow) * K + scol;
  else                  Apf = (const float*)Av + (long long)z * sA + (long long)(m0 + srow) * K + scol;

  f32x4 acc[4][4];
  #pragma unroll
  for (int i = 0; i < 4; i++)
    #pragma unroll
    for (int j = 0; j < 4; j++)
      acc[i][j] = (f32x4){0.f, 0.f, 0.f, 0.f};

  for (int k0 = 0; k0 < K; k0 += 32){
    if constexpr (A_BF16){
      const uint4 a0 = *(const uint4*)(Aph + k0);
      const uint4 a1 = *(const uint4*)(Aph + k0 + 8);
      *(uint4*)(&smA[srow * 40 + scol])     = a0;
      *(uint4*)(&smA[srow * 40 + scol + 8]) = a1;
    } else {
      const float4 f0 = *(const float4*)(Apf + k0);
      const float4 f1 = *(const float4*)(Apf + k0 + 4);
      const float4 f2 = *(const float4*)(Apf + k0 + 8);
      const float4 f3 = *(const float4*)(Apf + k0 + 12);
      u16x8 p0, p1;
      p0[0]=f2bf(f0.x); p0[1]=f2bf(f0.y); p0[2]=f2bf(f0.z); p0[3]=f2bf(f0.w);
      p0[4]=f2bf(f1.x); p0[5]=f2bf(f1.y); p0[6]=f2bf(f1.z); p0[7]=f2bf(f1.w);
      p1[0]=f2bf(f2.x); p1[1]=f2bf(f2.y); p1[2]=f2bf(f2.z); p1[3]=f2bf(f2.w);
      p1[4]=f2bf(f3.x); p1[5]=f2bf(f3.y); p1[6]=f2bf(f3.z); p1[7]=f2bf(f3.w);
      *(u16x8*)(&smA[srow * 40 + scol])     = p0;
      *(u16x8*)(&smA[srow * 40 + scol + 8]) = p1;
    }
    {
      const float4 f0 = *(const float4*)(Bp + k0);
      const float4 f1 = *(const float4*)(Bp + k0 + 4);
      const float4 f2 = *(const float4*)(Bp + k0 + 8);
      const float4 f3 = *(const float4*)(Bp + k0 + 12);
      u16x8 p0, p1;
      p0[0]=f2bf(f0.x); p0[1]=f2bf(f0.y); p0[2]=f2bf(f0.z); p0[3]=f2bf(f0.w);
      p0[4]=f2bf(f1.x); p0[5]=f2bf(f1.y); p0[6]=f2bf(f1.z); p0[7]=f2bf(f1.w);
      p1[0]=f2bf(f2.x); p1[1]=f2bf(f2.y); p1[2]=f2bf(f2.z); p1[3]=f2bf(f2.w);
      p1[4]=f2bf(f3.x); p1[5]=f2bf(f3.y); p1[6]=f2bf(f3.z); p1[7]=f2bf(f3.w);
      *(u16x8*)(&smB[srow * 40 + scol])     = p0;
      *(u16x8*)(&smB[srow * 40 + scol + 8]) = p1;
    }
    __syncthreads();
    bf16x8 aF[4], bF[4];
    #pragma unroll
    for (int i = 0; i < 4; i++) aF[i] = *(const bf16x8*)(&smA[(moff + i * 16 + l15) * 40 + quad * 8]);
    #pragma unroll
    for (int j = 0; j < 4; j++) bF[j] = *(const bf16x8*)(&smB[(noff + j * 16 + l15) * 40 + quad * 8]);
    #pragma unroll
    for (int i = 0; i < 4; i++)
      #pragma unroll
      for (int j = 0; j < 4; j++)
        acc[i][j] = __builtin_amdgcn_mfma_f32_16x16x32_bf16(aF[i], bF[j], acc[i][j], 0, 0, 0);
    __syncthreads();
  }

  const float* biasp = bias + (long long)z * sBias;
  const long long cbase = (long long)z * sC;
  #pragma unroll
  for (int j = 0; j < 4; j++){
    const int gn = n0 + noff + j * 16 + l15;
    const float bv = biasp[gn];
    #pragma unroll
    for (int i = 0; i < 4; i++){
      const int gmb = m0 + moff + i * 16 + quad * 4;   // C/D: m = quad*4+reg, n = lane&15
      #pragma unroll
      for (int r = 0; r < 4; r++){
        float v = acc[i][j][r] + bv;
        if constexpr (GELU_EP) v = gelu_tanh(v);
        const long long off = cbase + (long long)(gmb + r) * N + gn;
        if constexpr (OUT_BF16) ((u16*)Cv)[off] = f2bf(v);
        else                    ((float*)Cv)[off] = v;
      }
    }
  }
}

// -------------------------------------------------------- logits + loss -----
// One wave per row: logits[e] = h[i].cp_w2[e] + cp_b2[e];
// loss += sum_e softplus(l) - l*mask.
__global__ __launch_bounds__(256)
void loss_kernel(const u16* __restrict__ h, const float* __restrict__ cp_w2,
                 const float* __restrict__ cp_b2, const uint32* __restrict__ keep_bits,
                 float* __restrict__ loss)
{
  __shared__ float bl;
  if (threadIdx.x == 0) bl = 0.f;
  __syncthreads();
  const int wv = threadIdx.x >> 6, lane = threadIdx.x & 63;
  const int i  = blockIdx.x * 4 + wv;
  const u16* hr = h + (size_t)i * D_ + lane * 16;
  const uint4 ha = *(const uint4*)(hr);
  const uint4 hb = *(const uint4*)(hr + 8);
  float hx[16];
  hx[0]=bf_lo(ha.x); hx[1]=bf_hi(ha.x); hx[2]=bf_lo(ha.y); hx[3]=bf_hi(ha.y);
  hx[4]=bf_lo(ha.z); hx[5]=bf_hi(ha.z); hx[6]=bf_lo(ha.w); hx[7]=bf_hi(ha.w);
  hx[8]=bf_lo(hb.x); hx[9]=bf_hi(hb.x); hx[10]=bf_lo(hb.y); hx[11]=bf_hi(hb.y);
  hx[12]=bf_lo(hb.z); hx[13]=bf_hi(hb.z); hx[14]=bf_lo(hb.w); hx[15]=bf_hi(hb.w);
  float acc[NEXP];
  #pragma unroll
  for (int e = 0; e < NEXP; e++){
    const float* wr = cp_w2 + e * D_ + lane * 16;
    const float4 w0 = *(const float4*)(wr +  0);
    const float4 w1 = *(const float4*)(wr +  4);
    const float4 w2 = *(const float4*)(wr +  8);
    const float4 w3 = *(const float4*)(wr + 12);
    float s = hx[0]*w0.x + hx[1]*w0.y + hx[2]*w0.z + hx[3]*w0.w;
    s += hx[4]*w1.x + hx[5]*w1.y + hx[6]*w1.z + hx[7]*w1.w;
    s += hx[8]*w2.x + hx[9]*w2.y + hx[10]*w2.z + hx[11]*w2.w;
    s += hx[12]*w3.x + hx[13]*w3.y + hx[14]*w3.z + hx[15]*w3.w;
    acc[e] = s;
  }
  #pragma unroll
  for (int e = 0; e < NEXP; e++){
    #pragma unroll
    for (int off = 32; off >= 1; off >>= 1) acc[e] += __shfl_xor(acc[e], off);
  }
  if (lane == 0){
    const uint32 kb = keep_bits[i];
    float li = 0.f;
    #pragma unroll
    for (int e = 0; e < NEXP; e++){
      const float l  = acc[e] + cp_b2[e];
      const float sp = fmaxf(l, 0.f) + log1pf(expf(-fabsf(l)));
      li += sp - l * (float)((kb >> e) & 1u);
    }
    atomicAdd(&bl, li);
  }
  __syncthreads();
  if (threadIdx.x == 0) atomicAdd(loss, bl);
}

// ------------------------------------------------------------ LN gather -----
// Y[e*KCAP+r][:] = LN(x[rowlist[e*KCAP+r]]) * g + b, stored bf16.
__global__ __launch_bounds__(256)
void ln_gather_kernel(const float* __restrict__ x, const int* __restrict__ rowlist,
                      const float* __restrict__ ln_g, const float* __restrict__ ln_b,
                      u16* __restrict__ Y)
{
  __shared__ float red[8];
  const int b   = blockIdx.x;
  const int row = rowlist[b];
  const int tid = threadIdx.x;
  const float4 v = *(const float4*)(x + (size_t)row * D_ + tid * 4);
  float s = v.x + v.y + v.z + v.w;
  float q = v.x*v.x + v.y*v.y + v.z*v.z + v.w*v.w;
  const int lane = tid & 63, wv = tid >> 6;
  #pragma unroll
  for (int off = 32; off >= 1; off >>= 1){ s += __shfl_xor(s, off); q += __shfl_xor(q, off); }
  if (lane == 0){ red[wv] = s; red[4 + wv] = q; }
  __syncthreads();
  s = red[0] + red[1] + red[2] + red[3];
  q = red[4] + red[5] + red[6] + red[7];
  const float mu  = s * (1.0f / D_);
  const float var = q * (1.0f / D_) - mu * mu;
  const float rs  = rsqrtf(var + 1e-5f);
  const float4 g  = *(const float4*)(ln_g + tid * 4);
  const float4 bb = *(const float4*)(ln_b + tid * 4);
  u16x4 o;
  o[0] = f2bf((v.x - mu) * rs * g.x + bb.x);
  o[1] = f2bf((v.y - mu) * rs * g.y + bb.y);
  o[2] = f2bf((v.z - mu) * rs * g.z + bb.z);
  o[3] = f2bf((v.w - mu) * rs * g.w + bb.w);
  *(u16x4*)(&Y[(size_t)b * D_ + tid * 4]) = o;
}

// -------------------------------------------------------------- combine -----
// out[i] = x[i] + sum_{e in keep_bits[i]} wlist[e][inv] * Y2[e][inv][:]
__global__ __launch_bounds__(256)
void combine_kernel(const float* __restrict__ x, const uint32* __restrict__ keep_bits,
                    const int* __restrict__ inv, const float* __restrict__ wlist,
                    const float* __restrict__ Y2, float* __restrict__ out)
{
  const int i = blockIdx.x;
  const int c = threadIdx.x * 4;
  float4 v = *(const float4*)(x + (size_t)i * D_ + c);
  uint32 kb = keep_bits[i];
  while (kb){
    const int e = __ffs(kb) - 1;
    kb &= kb - 1;
    const int r = inv[i * NEXP + e];
    const float w = wlist[e * KCAP + r];
    const float4 y = *(const float4*)(Y2 + ((size_t)(e * KCAP + r)) * D_ + c);
    v.x += w * y.x; v.y += w * y.y; v.z += w * y.z; v.w += w * y.w;
  }
  *(float4*)(out + (size_t)i * D_ + c) = v;
}

__global__ void finalize_loss_kernel(const float* __restrict__ loss, float* __restrict__ outp){
  outp[0] = loss[0] * (1.0f / (float)(BS_ * NEXP));
}

// ---------------------------------------------------------------- launch ----
extern "C" void kernel_launch(void* const* d_in, const int* in_sizes, int n_in,
                              void* d_out, int out_size, void* d_ws, size_t ws_size,
                              hipStream_t stream)
{
  const float* x     = (const float*)d_in[0];
  const float* Wg    = (const float*)d_in[1];
  const float* cp_w1 = (const float*)d_in[2];
  const float* cp_b1 = (const float*)d_in[3];
  const float* cp_w2 = (const float*)d_in[4];
  const float* cp_b2 = (const float*)d_in[5];
  const float* ln_g  = (const float*)d_in[6];
  const float* ln_b  = (const float*)d_in[7];
  const float* fc1s  = (const float*)d_in[8];
  const float* b1s   = (const float*)d_in[9];
  const float* fc2s  = (const float*)d_in[10];
  const float* b2s   = (const float*)d_in[11];
  float* out = (float*)d_out;

  char* p = (char*)d_ws;
  auto take = [&](size_t bytes) -> char* {
    char* r = p; p += (bytes + 255) & ~(size_t)255; return r;
  };
  float*  scores    = (float*) take((size_t)BS_ * NEXP * 4);
  int*    counts    = (int*)   take(256);                    // [8], memset 0
  float*  loss      = (float*) take(256);                    // scalar, memset 0
  int*    rowlist   = (int*)   take((size_t)BS_ * 4);        // [NEXP][KCAP]
  float*  wlist     = (float*) take((size_t)BS_ * 4);        // [NEXP][KCAP]
  uint32* keep_bits = (uint32*)take((size_t)BS_ * 4);
  int*    inv       = (int*)   take((size_t)BS_ * NEXP * 4);
  u16*    h_cp      = (u16*)   take((size_t)BS_ * D_ * 2);         // 16 MB
  u16*    Y         = (u16*)   take((size_t)NEXP * KCAP * D_ * 2); // 16 MB
  u16*    H1        = (u16*)   take((size_t)NEXP * KCAP * DD_ * 2);// 64 MB
  float*  Y2        = (float*) take((size_t)NEXP * KCAP * D_ * 4); // 32 MB

  hipMemsetAsync(counts, 0, 512, stream);   // counts + loss (adjacent takes)

  gating_kernel<<<BS_, 64, 0, stream>>>(x, Wg, scores, keep_bits);

  select_kernel<<<dim3(BS_ / 256, NEXP), 256, 0, stream>>>(
      scores, keep_bits, counts, rowlist, wlist, inv);

  // cp path: h = gelu(x @ cp_w1^T + cp_b1)  [8192x1024, K=1024]
  gemm_bt<false, true, true><<<dim3(D_ / 128, BS_ / 128, 1), 256, 0, stream>>>(
      x, cp_w1, cp_b1, h_cp, BS_, D_, D_, 0, 0, 0, 0);

  loss_kernel<<<BS_ / 4, 256, 0, stream>>>(h_cp, cp_w2, cp_b2, keep_bits, loss);

  ln_gather_kernel<<<BS_, 256, 0, stream>>>(x, rowlist, ln_g, ln_b, Y);

  // fc1: H1[e] = gelu(Y[e] @ fc1s[e]^T + b1s[e])  [1024x4096, K=1024] x8
  gemm_bt<true, true, true><<<dim3(DD_ / 128, KCAP / 128, NEXP), 256, 0, stream>>>(
      Y, fc1s, b1s, H1, KCAP, DD_, D_,
      (long long)KCAP * D_, (long long)DD_ * D_, DD_, (long long)KCAP * DD_);

  // fc2: Y2[e] = H1[e] @ fc2s[e]^T + b2s[e]  [1024x1024, K=4096] x8
  gemm_bt<true, false, false><<<dim3(D_ / 128, KCAP / 128, NEXP), 256, 0, stream>>>(
      H1, fc2s, b2s, Y2, KCAP, D_, DD_,
      (long long)KCAP * DD_, (long long)D_ * DD_, D_, (long long)KCAP * D_);

  combine_kernel<<<BS_, 256, 0, stream>>>(x, keep_bits, inv, wlist, Y2, out);

  finalize_loss_kernel<<<1, 1, 0, stream>>>(loss, out + (size_t)BS_ * D_);
}

// Round 2
// 871.350 us; speedup vs baseline: 1.0060x; 1.0060x over previous
//
#include <hip/hip_runtime.h>

// DiffMoE fused step, MI355X gfx950. Round 2.
// Changes vs R1: weights pre-converted to bf16 (one memory-bound pass),
// gating emits bf16 x; GEMM rewritten to m97 structure (global_load_lds
// width=16 staging, non-padded 128x32 LDS tiles, ds_read_b128 fragments).

#define BS_   8192
#define D_    1024
#define DD_   4096
#define NEXP  8
#define KCAP  1024

typedef unsigned int   uint32;
typedef unsigned short u16;
typedef __bf16 bf16x8  __attribute__((ext_vector_type(8)));
typedef float  f32x4   __attribute__((ext_vector_type(4)));
typedef u16    u16x8   __attribute__((ext_vector_type(8)));
typedef u16    u16x4   __attribute__((ext_vector_type(4)));

__device__ __forceinline__ u16 f2bf(float f){
  uint32 u = __float_as_uint(f);
  u = (u + 0x7fffu + ((u >> 16) & 1u)) >> 16;   // RNE
  return (u16)u;
}
__device__ __forceinline__ float bf_lo(uint32 u){ return __uint_as_float(u << 16); }
__device__ __forceinline__ float bf_hi(uint32 u){ return __uint_as_float(u & 0xffff0000u); }
__device__ __forceinline__ float gelu_tanh(float v){
  return 0.5f * v * (1.0f + tanhf(0.7978845608028654f * (v + 0.044715f * v * v * v)));
}
__device__ __forceinline__ void glds16(const u16* g, u16* l){
  __builtin_amdgcn_global_load_lds(
      (const __attribute__((address_space(1))) unsigned int*)g,
      (__attribute__((address_space(3))) unsigned int*)l, 16, 0, 0);
}

// --------------------------------------------------------------- convert ----
// fp32 -> bf16, 8 elements/thread, grid-stride.
__global__ __launch_bounds__(256)
void convert_kernel(const float* __restrict__ in, u16* __restrict__ out, int n)
{
  const int stride = gridDim.x * 256 * 8;
  for (int idx = (blockIdx.x * 256 + threadIdx.x) * 8; idx < n; idx += stride){
    const float4 a = *(const float4*)(in + idx);
    const float4 b = *(const float4*)(in + idx + 4);
    u16x8 o;
    o[0]=f2bf(a.x); o[1]=f2bf(a.y); o[2]=f2bf(a.z); o[3]=f2bf(a.w);
    o[4]=f2bf(b.x); o[5]=f2bf(b.y); o[6]=f2bf(b.z); o[7]=f2bf(b.w);
    *(u16x8*)(out + idx) = o;
  }
}

// ---------------------------------------------------------------- gating ----
// scores[i][e] = (tanh(x[i].Wg[e]) + 1) * 0.5 ; zero keep_bits; emit bf16 x.
__global__ __launch_bounds__(64)
void gating_kernel(const float* __restrict__ x, const float* __restrict__ Wg,
                   float* __restrict__ scores, uint32* __restrict__ keep_bits,
                   u16* __restrict__ xh)
{
  const int i    = blockIdx.x;
  const int lane = threadIdx.x;
  const float* xr = x + (size_t)i * D_ + lane * 16;
  const float4 x0 = *(const float4*)(xr +  0);
  const float4 x1 = *(const float4*)(xr +  4);
  const float4 x2 = *(const float4*)(xr +  8);
  const float4 x3 = *(const float4*)(xr + 12);
  // bf16 side product
  u16x8 p0, p1;
  p0[0]=f2bf(x0.x); p0[1]=f2bf(x0.y); p0[2]=f2bf(x0.z); p0[3]=f2bf(x0.w);
  p0[4]=f2bf(x1.x); p0[5]=f2bf(x1.y); p0[6]=f2bf(x1.z); p0[7]=f2bf(x1.w);
  p1[0]=f2bf(x2.x); p1[1]=f2bf(x2.y); p1[2]=f2bf(x2.z); p1[3]=f2bf(x2.w);
  p1[4]=f2bf(x3.x); p1[5]=f2bf(x3.y); p1[6]=f2bf(x3.z); p1[7]=f2bf(x3.w);
  *(u16x8*)(xh + (size_t)i * D_ + lane * 16)     = p0;
  *(u16x8*)(xh + (size_t)i * D_ + lane * 16 + 8) = p1;

  float acc[NEXP];
  #pragma unroll
  for (int e = 0; e < NEXP; e++){
    const float* wr = Wg + e * D_ + lane * 16;
    const float4 w0 = *(const float4*)(wr +  0);
    const float4 w1 = *(const float4*)(wr +  4);
    const float4 w2 = *(const float4*)(wr +  8);
    const float4 w3 = *(const float4*)(wr + 12);
    float s = x0.x*w0.x + x0.y*w0.y + x0.z*w0.z + x0.w*w0.w;
    s += x1.x*w1.x + x1.y*w1.y + x1.z*w1.z + x1.w*w1.w;
    s += x2.x*w2.x + x2.y*w2.y + x2.z*w2.z + x2.w*w2.w;
    s += x3.x*w3.x + x3.y*w3.y + x3.z*w3.z + x3.w*w3.w;
    acc[e] = s;
  }
  #pragma unroll
  for (int e = 0; e < NEXP; e++){
    #pragma unroll
    for (int off = 32; off >= 1; off >>= 1) acc[e] += __shfl_xor(acc[e], off);
  }
  if (lane == 0){
    #pragma unroll
    for (int e = 0; e < NEXP; e++) scores[i * NEXP + e] = (tanhf(acc[e]) + 1.0f) * 0.5f;
    keep_bits[i] = 0u;
  }
}

// ------------------------------------------------------------- selection ----
// Exact top-k via rank count; key = (score_bits<<32)|(8191-i): higher score
// wins, ties -> lower index (matches stable argsort of -scores). Inner loop
// reads sk[jj] at a wave-uniform address -> LDS broadcast, no conflicts.
__global__ __launch_bounds__(256)
void select_kernel(const float* __restrict__ scores, uint32* __restrict__ keep_bits,
                   int* __restrict__ counts, int* __restrict__ rowlist,
                   float* __restrict__ wlist, int* __restrict__ inv)
{
  __shared__ unsigned long long sk[2048];
  const int e = blockIdx.y;
  const int i = blockIdx.x * 256 + threadIdx.x;
  const float ms = scores[i * NEXP + e];
  const unsigned long long mk =
      ((unsigned long long)__float_as_uint(ms) << 32) | (uint32)(BS_ - 1 - i);
  int cnt = 0;
  for (int base = 0; base < BS_; base += 2048){
    #pragma unroll
    for (int u = 0; u < 8; u++){
      const int j = base + (int)threadIdx.x * 8 + u;
      const float sj = scores[j * NEXP + e];
      sk[threadIdx.x * 8 + u] =
          ((unsigned long long)__float_as_uint(sj) << 32) | (uint32)(BS_ - 1 - j);
    }
    __syncthreads();
    #pragma unroll 8
    for (int jj = 0; jj < 2048; jj++) cnt += (sk[jj] > mk) ? 1 : 0;
    __syncthreads();
  }
  if (cnt < KCAP){
    const int slot = atomicAdd(&counts[e], 1);
    rowlist[e * KCAP + slot] = i;
    wlist[e * KCAP + slot]   = ms;
    inv[i * NEXP + e]        = slot;
    atomicOr(&keep_bits[i], 1u << e);
  }
}

// ------------------------------------------------------------------ GEMM ----
// C[m][n] = sum_k A[m][k]*B[n][k] (+bias[n], opt gelu). A,B bf16 (both K-major).
// m97 structure: 128x128 tile, BK=32, global_load_lds width=16 staging into
// non-padded 128x32 LDS, ds_read_b128 fragments, 4 waves x (4x4) MFMA 16x16x32.
template<bool GELU_EP, bool OUT_BF16>
__global__ __launch_bounds__(256)
void gemm_bt16(const u16* __restrict__ A, const u16* __restrict__ B,
               const float* __restrict__ bias, void* __restrict__ Cv,
               int M, int N, int K,
               long long sA, long long sB, long long sBias, long long sC)
{
  __shared__ u16 smA[128 * 32];
  __shared__ u16 smB[128 * 32];
  const int z    = blockIdx.z;
  const int m0   = blockIdx.y * 128;
  const int n0   = blockIdx.x * 128;
  const int tid  = threadIdx.x;
  const int lane = tid & 63, wv = tid >> 6;
  const int l15  = lane & 15, quad = lane >> 4;
  const int moff = (wv >> 1) * 64, noff = (wv & 1) * 64;

  // staging: wave w chunk c covers LDS rows w*32+c*16+lane/4, k-col (lane&3)*8
  const int srow = wv * 32 + (lane >> 2);
  const int skol = (lane & 3) * 8;
  const u16* Ag = A + (long long)z * sA + (long long)(m0 + srow) * K + skol;
  const u16* Bg = B + (long long)z * sB + (long long)(n0 + srow) * K + skol;
  u16* lA = smA + wv * 1024;   // wave-uniform LDS base (+lane*16B implicit)
  u16* lB = smB + wv * 1024;

  f32x4 acc[4][4];
  #pragma unroll
  for (int i = 0; i < 4; i++)
    #pragma unroll
    for (int j = 0; j < 4; j++)
      acc[i][j] = (f32x4){0.f, 0.f, 0.f, 0.f};

  for (int k0 = 0; k0 < K; k0 += 32){
    #pragma unroll
    for (int c = 0; c < 2; c++){
      glds16(Ag + (long long)(c * 16) * K + k0, lA + c * 512);
      glds16(Bg + (long long)(c * 16) * K + k0, lB + c * 512);
    }
    __syncthreads();
    bf16x8 aF[4], bF[4];
    #pragma unroll
    for (int i = 0; i < 4; i++)
      aF[i] = *(const bf16x8*)(smA + (moff + i * 16 + l15) * 32 + quad * 8);
    #pragma unroll
    for (int j = 0; j < 4; j++)
      bF[j] = *(const bf16x8*)(smB + (noff + j * 16 + l15) * 32 + quad * 8);
    #pragma unroll
    for (int i = 0; i < 4; i++)
      #pragma unroll
      for (int j = 0; j < 4; j++)
        acc[i][j] = __builtin_amdgcn_mfma_f32_16x16x32_bf16(aF[i], bF[j], acc[i][j], 0, 0, 0);
    __syncthreads();
  }

  const float* biasp = bias + (long long)z * sBias;
  const long long cbase = (long long)z * sC;
  #pragma unroll
  for (int j = 0; j < 4; j++){
    const int gn = n0 + noff + j * 16 + l15;
    const float bv = biasp[gn];
    #pragma unroll
    for (int i = 0; i < 4; i++){
      const int gmb = m0 + moff + i * 16 + quad * 4;   // C/D: m = quad*4+reg, n = lane&15
      #pragma unroll
      for (int r = 0; r < 4; r++){
        float v = acc[i][j][r] + bv;
        if constexpr (GELU_EP) v = gelu_tanh(v);
        const long long off = cbase + (long long)(gmb + r) * N + gn;
        if constexpr (OUT_BF16) ((u16*)Cv)[off] = f2bf(v);
        else                    ((float*)Cv)[off] = v;
      }
    }
  }
}

// -------------------------------------------------------- logits + loss -----
__global__ __launch_bounds__(256)
void loss_kernel(const u16* __restrict__ h, const float* __restrict__ cp_w2,
                 const float* __restrict__ cp_b2, const uint32* __restrict__ keep_bits,
                 float* __restrict__ loss)
{
  __shared__ float bl;
  if (threadIdx.x == 0) bl = 0.f;
  __syncthreads();
  const int wv = threadIdx.x >> 6, lane = threadIdx.x & 63;
  const int i  = blockIdx.x * 4 + wv;
  const u16* hr = h + (size_t)i * D_ + lane * 16;
  const uint4 ha = *(const uint4*)(hr);
  const uint4 hb = *(const uint4*)(hr + 8);
  float hx[16];
  hx[0]=bf_lo(ha.x); hx[1]=bf_hi(ha.x); hx[2]=bf_lo(ha.y); hx[3]=bf_hi(ha.y);
  hx[4]=bf_lo(ha.z); hx[5]=bf_hi(ha.z); hx[6]=bf_lo(ha.w); hx[7]=bf_hi(ha.w);
  hx[8]=bf_lo(hb.x); hx[9]=bf_hi(hb.x); hx[10]=bf_lo(hb.y); hx[11]=bf_hi(hb.y);
  hx[12]=bf_lo(hb.z); hx[13]=bf_hi(hb.z); hx[14]=bf_lo(hb.w); hx[15]=bf_hi(hb.w);
  float acc[NEXP];
  #pragma unroll
  for (int e = 0; e < NEXP; e++){
    const float* wr = cp_w2 + e * D_ + lane * 16;
    const float4 w0 = *(const float4*)(wr +  0);
    const float4 w1 = *(const float4*)(wr +  4);
    const float4 w2 = *(const float4*)(wr +  8);
    const float4 w3 = *(const float4*)(wr + 12);
    float s = hx[0]*w0.x + hx[1]*w0.y + hx[2]*w0.z + hx[3]*w0.w;
    s += hx[4]*w1.x + hx[5]*w1.y + hx[6]*w1.z + hx[7]*w1.w;
    s += hx[8]*w2.x + hx[9]*w2.y + hx[10]*w2.z + hx[11]*w2.w;
    s += hx[12]*w3.x + hx[13]*w3.y + hx[14]*w3.z + hx[15]*w3.w;
    acc[e] = s;
  }
  #pragma unroll
  for (int e = 0; e < NEXP; e++){
    #pragma unroll
    for (int off = 32; off >= 1; off >>= 1) acc[e] += __shfl_xor(acc[e], off);
  }
  if (lane == 0){
    const uint32 kb = keep_bits[i];
    float li = 0.f;
    #pragma unroll
    for (int e = 0; e < NEXP; e++){
      const float l  = acc[e] + cp_b2[e];
      const float sp = fmaxf(l, 0.f) + log1pf(expf(-fabsf(l)));
      li += sp - l * (float)((kb >> e) & 1u);
    }
    atomicAdd(&bl, li);
  }
  __syncthreads();
  if (threadIdx.x == 0) atomicAdd(loss, bl);
}

// ------------------------------------------------------------ LN gather -----
__global__ __launch_bounds__(256)
void ln_gather_kernel(const float* __restrict__ x, const int* __restrict__ rowlist,
                      const float* __restrict__ ln_g, const float* __restrict__ ln_b,
                      u16* __restrict__ Y)
{
  __shared__ float red[8];
  const int b   = blockIdx.x;
  const int row = rowlist[b];
  const int tid = threadIdx.x;
  const float4 v = *(const float4*)(x + (size_t)row * D_ + tid * 4);
  float s = v.x + v.y + v.z + v.w;
  float q = v.x*v.x + v.y*v.y + v.z*v.z + v.w*v.w;
  const int lane = tid & 63, wv = tid >> 6;
  #pragma unroll
  for (int off = 32; off >= 1; off >>= 1){ s += __shfl_xor(s, off); q += __shfl_xor(q, off); }
  if (lane == 0){ red[wv] = s; red[4 + wv] = q; }
  __syncthreads();
  s = red[0] + red[1] + red[2] + red[3];
  q = red[4] + red[5] + red[6] + red[7];
  const float mu  = s * (1.0f / D_);
  const float var = q * (1.0f / D_) - mu * mu;
  const float rs  = rsqrtf(var + 1e-5f);
  const float4 g  = *(const float4*)(ln_g + tid * 4);
  const float4 bb = *(const float4*)(ln_b + tid * 4);
  u16x4 o;
  o[0] = f2bf((v.x - mu) * rs * g.x + bb.x);
  o[1] = f2bf((v.y - mu) * rs * g.y + bb.y);
  o[2] = f2bf((v.z - mu) * rs * g.z + bb.z);
  o[3] = f2bf((v.w - mu) * rs * g.w + bb.w);
  *(u16x4*)(&Y[(size_t)b * D_ + tid * 4]) = o;
}

// -------------------------------------------------------------- combine -----
__global__ __launch_bounds__(256)
void combine_kernel(const float* __restrict__ x, const uint32* __restrict__ keep_bits,
                    const int* __restrict__ inv, const float* __restrict__ wlist,
                    const float* __restrict__ Y2, float* __restrict__ out)
{
  const int i = blockIdx.x;
  const int c = threadIdx.x * 4;
  float4 v = *(const float4*)(x + (size_t)i * D_ + c);
  uint32 kb = keep_bits[i];
  while (kb){
    const int e = __ffs(kb) - 1;
    kb &= kb - 1;
    const int r = inv[i * NEXP + e];
    const float w = wlist[e * KCAP + r];
    const float4 y = *(const float4*)(Y2 + ((size_t)(e * KCAP + r)) * D_ + c);
    v.x += w * y.x; v.y += w * y.y; v.z += w * y.z; v.w += w * y.w;
  }
  *(float4*)(out + (size_t)i * D_ + c) = v;
}

__global__ void finalize_loss_kernel(const float* __restrict__ loss, float* __restrict__ outp){
  outp[0] = loss[0] * (1.0f / (float)(BS_ * NEXP));
}

// ---------------------------------------------------------------- launch ----
extern "C" void kernel_launch(void* const* d_in, const int* in_sizes, int n_in,
                              void* d_out, int out_size, void* d_ws, size_t ws_size,
                              hipStream_t stream)
{
  const float* x     = (const float*)d_in[0];
  const float* Wg    = (const float*)d_in[1];
  const float* cp_w1 = (const float*)d_in[2];
  const float* cp_b1 = (const float*)d_in[3];
  const float* cp_w2 = (const float*)d_in[4];
  const float* cp_b2 = (const float*)d_in[5];
  const float* ln_g  = (const float*)d_in[6];
  const float* ln_b  = (const float*)d_in[7];
  const float* fc1s  = (const float*)d_in[8];
  const float* b1s   = (const float*)d_in[9];
  const float* fc2s  = (const float*)d_in[10];
  const float* b2s   = (const float*)d_in[11];
  float* out = (float*)d_out;

  char* p = (char*)d_ws;
  auto take = [&](size_t bytes) -> char* {
    char* r = p; p += (bytes + 255) & ~(size_t)255; return r;
  };
  float*  scores    = (float*) take((size_t)BS_ * NEXP * 4);
  int*    counts    = (int*)   take(256);                    // [8], memset 0
  float*  loss      = (float*) take(256);                    // scalar, memset 0
  int*    rowlist   = (int*)   take((size_t)BS_ * 4);        // [NEXP][KCAP]
  float*  wlist     = (float*) take((size_t)BS_ * 4);
  uint32* keep_bits = (uint32*)take((size_t)BS_ * 4);
  int*    inv       = (int*)   take((size_t)BS_ * NEXP * 4);
  u16*    xh        = (u16*)   take((size_t)BS_ * D_ * 2);            // 16 MB
  u16*    cpw1h     = (u16*)   take((size_t)D_ * D_ * 2);             //  2 MB
  u16*    fc1h      = (u16*)   take((size_t)NEXP * DD_ * D_ * 2);     // 64 MB
  u16*    fc2h      = (u16*)   take((size_t)NEXP * D_ * DD_ * 2);     // 64 MB
  u16*    H1        = (u16*)   take((size_t)NEXP * KCAP * DD_ * 2);   // 64 MB
  u16*    h_cp      = (u16*)   take((size_t)BS_ * D_ * 2);            // 16 MB
  u16*    Y         = (u16*)   take((size_t)NEXP * KCAP * D_ * 2);    // 16 MB
  float*  Y2        = (float*)h_cp;   // 32 MB alias over h_cp+Y (both dead by fc2)

  hipMemsetAsync(counts, 0, 512, stream);   // counts + loss (adjacent takes)

  // weight conversions (independent of everything else)
  convert_kernel<<<512,  256, 0, stream>>>(cp_w1, cpw1h, D_ * D_);
  convert_kernel<<<8192, 256, 0, stream>>>(fc1s, fc1h, NEXP * DD_ * D_);
  convert_kernel<<<8192, 256, 0, stream>>>(fc2s, fc2h, NEXP * D_ * DD_);

  gating_kernel<<<BS_, 64, 0, stream>>>(x, Wg, scores, keep_bits, xh);

  select_kernel<<<dim3(BS_ / 256, NEXP), 256, 0, stream>>>(
      scores, keep_bits, counts, rowlist, wlist, inv);

  // cp path: h = gelu(x @ cp_w1^T + cp_b1)  [8192x1024, K=1024]
  gemm_bt16<true, true><<<dim3(D_ / 128, BS_ / 128, 1), 256, 0, stream>>>(
      xh, cpw1h, cp_b1, h_cp, BS_, D_, D_, 0, 0, 0, 0);

  loss_kernel<<<BS_ / 4, 256, 0, stream>>>(h_cp, cp_w2, cp_b2, keep_bits, loss);

  ln_gather_kernel<<<BS_, 256, 0, stream>>>(x, rowlist, ln_g, ln_b, Y);

  // fc1: H1[e] = gelu(Y[e] @ fc1s[e]^T + b1s[e])  [1024x4096, K=1024] x8
  gemm_bt16<true, true><<<dim3(DD_ / 128, KCAP / 128, NEXP), 256, 0, stream>>>(
      Y, fc1h, b1s, H1, KCAP, DD_, D_,
      (long long)KCAP * D_, (long long)DD_ * D_, DD_, (long long)KCAP * DD_);

  // fc2: Y2[e] = H1[e] @ fc2s[e]^T + b2s[e]  [1024x1024, K=4096] x8
  gemm_bt16<false, false><<<dim3(D_ / 128, KCAP / 128, NEXP), 256, 0, stream>>>(
      H1, fc2h, b2s, Y2, KCAP, D_, DD_,
      (long long)KCAP * DD_, (long long)D_ * DD_, D_, (long long)KCAP * D_);

  combine_kernel<<<BS_, 256, 0, stream>>>(x, keep_bits, inv, wlist, Y2, out);

  finalize_loss_kernel<<<1, 1, 0, stream>>>(loss, out + (size_t)BS_ * D_);
}